// Round 4
// baseline (181.566 us; speedup 1.0000x reference)
//
#include <hip/hip_runtime.h>
#include <hip/hip_bf16.h>

#define B_  4
#define C_  256
#define C2_ 128
#define N_  4096
#define LOG2E 1.4426950408889634f

typedef unsigned short u16;
typedef __attribute__((ext_vector_type(8))) short bf16x8;  // 8 bf16 in 4 VGPRs
typedef __attribute__((ext_vector_type(4))) float f32x4;

static __device__ __forceinline__ u16 f2bf(float f) {
    return __builtin_bit_cast(u16, __float2bfloat16(f));
}
static __device__ __forceinline__ float bf2f(u16 u) {
    return __bfloat162float(__builtin_bit_cast(__hip_bfloat16, u));
}
static __device__ __forceinline__ bf16x8 cvt8(const float* p) {
    u16 t[8];
#pragma unroll
    for (int j = 0; j < 8; ++j) t[j] = f2bf(p[j]);
    return *(const bf16x8*)t;
}

// ---------------------------------------------------------------------------
// Kernel 0 (prep): one-shot fp32 -> bf16 weight conversion.
// Wb[3][128][256] (wt,wp,wg) and Wob[256][128] (w_out).
// ---------------------------------------------------------------------------
__global__ __launch_bounds__(256) void prep_kernel(
    const float* __restrict__ wt, const float* __restrict__ wp,
    const float* __restrict__ wg, const float* __restrict__ wo,
    u16* __restrict__ Wb, u16* __restrict__ Wob) {
    int g = (blockIdx.x * 256 + threadIdx.x) * 8;
    const float* src;
    u16* dst;
    if (g < 3 * 32768) {
        int mat = g >> 15;
        src = (mat == 0 ? wt : mat == 1 ? wp : wg) + (g & 32767);
        dst = Wb + g;
    } else {
        src = wo + (g & 32767);
        dst = Wob + (g & 32767);
    }
    float w8[8];
    *(float4*)&w8[0] = *(const float4*)src;
    *(float4*)&w8[4] = *(const float4*)(src + 4);
    *(bf16x8*)dst = cvt8(w8);
}

// ---------------------------------------------------------------------------
// Kernel 0b (xpose): x [B][C][N] fp32 -> XT [B*N][C] bf16, 64x64 LDS tiles.
// Pure-bandwidth transpose (~25 MB) done ONCE so projx never needs an
// in-block transpose or any barrier. Grid B*(C/64)*(N/64) = 1024.
// ---------------------------------------------------------------------------
__global__ __launch_bounds__(256) void xpose_kernel(
    const float* __restrict__ x, u16* __restrict__ XT) {
    __shared__ __align__(16) u16 Ts[64][72];   // 144B rows: uint4-aligned
    int bid = blockIdx.x;
    int b = bid >> 8, rem = bid & 255;
    int c0 = (rem >> 6) * 64, n0 = (rem & 63) * 64;
    int tid = threadIdx.x;
#pragma unroll
    for (int it = 0; it < 2; ++it) {
        int idx = it * 256 + tid;          // 512 items: c-pair p, n-quad q
        int q = idx & 15, p = idx >> 4;
        const float* r0 = x + ((size_t)b * C_ + c0 + 2 * p) * N_ + n0 + 4 * q;
        float4 v0 = *(const float4*)r0;
        float4 v1 = *(const float4*)(r0 + N_);
        const float* f0 = (const float*)&v0;
        const float* f1 = (const float*)&v1;
#pragma unroll
        for (int j = 0; j < 4; ++j) {
            unsigned pk = (unsigned)f2bf(f0[j]) | ((unsigned)f2bf(f1[j]) << 16);
            *(unsigned*)&Ts[4 * q + j][2 * p] = pk;
        }
    }
    __syncthreads();
#pragma unroll
    for (int it = 0; it < 2; ++it) {
        int idx = it * 256 + tid;          // 64 rows x 8 chunks
        int row = idx >> 3, ch = (idx & 7) * 8;
        *(uint4*)(XT + ((size_t)(b * N_ + n0 + row)) * C_ + c0 + ch) =
            *(const uint4*)&Ts[row][ch];
    }
}

// ---------------------------------------------------------------------------
// Kernel 1 (projx): pure MFMA GEMM, NO LDS staging, NO barriers (except the
// V-epilogue bounce in mat==2 blocks). Both fragment operands are direct,
// k-contiguous 16B global loads (XT rows / Wb rows, L2/L3-hot).
// Grid 1536 = 256 n-tiles x (3 mats x 2 c2-halves); ~4 blocks/CU.
// ---------------------------------------------------------------------------
__global__ __launch_bounds__(256, 2) void projx_kernel(
    const u16* __restrict__ XT, const u16* __restrict__ Wb,
    const float* __restrict__ b_theta, const float* __restrict__ b_phi,
    const float* __restrict__ b_g,
    u16* __restrict__ Q, u16* __restrict__ K, u16* __restrict__ V) {
    __shared__ __align__(16) u16 Vt[64][72];   // 9216 B, used by mat==2 only

    int bid = blockIdx.x;
    int nt  = bid & 255;           // n-tile over B*N (64 per b)
    int cm  = bid >> 8;            // 0..5
    int mat = cm >> 1, h = cm & 1;
    int b   = nt >> 6;
    int n0  = (nt & 63) * 64;
    int tid = threadIdx.x;
    int wave = tid >> 6, lane = tid & 63, quad = (lane >> 4) & 3, l16 = lane & 15;

    // A-frags: direct from XT (k = c contiguous)
    const u16* xrow = XT + ((size_t)(b * N_ + n0 + wave * 16 + l16)) * C_ + quad * 8;
    bf16x8 af[8];
#pragma unroll
    for (int ks = 0; ks < 8; ++ks)
        af[ks] = *(const bf16x8*)(xrow + ks * 32);

    const float* bias = mat == 0 ? b_theta : mat == 1 ? b_phi : b_g;

    f32x4 acc[4];
#pragma unroll
    for (int i = 0; i < 4; ++i) acc[i] = (f32x4){0.f, 0.f, 0.f, 0.f};

#pragma unroll
    for (int ct = 0; ct < 4; ++ct) {
        const u16* wrow = Wb + mat * 32768 +
                          (size_t)(h * 64 + ct * 16 + l16) * 256 + quad * 8;
        bf16x8 bfr[8];
#pragma unroll
        for (int ks = 0; ks < 8; ++ks)
            bfr[ks] = *(const bf16x8*)(wrow + ks * 32);
#pragma unroll
        for (int ks = 0; ks < 8; ++ks)
            acc[ct] = __builtin_amdgcn_mfma_f32_16x16x32_bf16(
                af[ks], bfr[ks], acc[ct], 0, 0, 0);
    }

    if (mat < 2) {
        u16* dst = mat == 0 ? Q : K;
        float scl = mat == 0 ? LOG2E : 1.0f;
#pragma unroll
        for (int ct = 0; ct < 4; ++ct) {
            int c2 = h * 64 + ct * 16 + l16;
            float bb = bias[c2];
#pragma unroll
            for (int r = 0; r < 4; ++r) {
                int n = n0 + wave * 16 + quad * 4 + r;
                dst[((size_t)b * N_ + n) * C2_ + c2] =
                    f2bf((acc[ct][r] + bb) * scl);
            }
        }
    } else {
        // V needs [b][c2][n]: bounce through LDS for coalesced 16B writes
#pragma unroll
        for (int ct = 0; ct < 4; ++ct) {
            int c2l = ct * 16 + l16;
            float bb = bias[h * 64 + c2l];
#pragma unroll
            for (int r = 0; r < 4; ++r)
                Vt[c2l][wave * 16 + quad * 4 + r] = f2bf(acc[ct][r] + bb);
        }
        __syncthreads();
#pragma unroll
        for (int it = 0; it < 2; ++it) {
            int idx = it * 256 + tid;
            int row = idx >> 3, n8 = (idx & 7) * 8;
            *(uint4*)(V + ((size_t)b * C2_ + h * 64 + row) * N_ + n0 + n8) =
                *(const uint4*)&Vt[row][n8];
        }
    }
}

// ---------------------------------------------------------------------------
// Kernel 2: flash attention — EXACT R-1 proven body (55 µs): b128 LDS reads
// with +8 pads (4.7M conflict-cycles measured CHEAPER than b64-pair fix),
// separate per-wave Psb, 2 barriers/tile, S=4.
// ---------------------------------------------------------------------------
__global__ __launch_bounds__(256, 2) void attn_kernel(
    const u16* __restrict__ Q, const u16* __restrict__ K,
    const u16* __restrict__ V, u16* __restrict__ AO,
    u16* __restrict__ Opb, float* __restrict__ lsum, int nsplit) {
    const int BM = 128, BN = 64, D = C2_;
    const int per = B_ * (N_ / BM);      // 128
    int s    = blockIdx.x / per;
    int r0   = blockIdx.x % per;
    int b    = r0 / (N_ / BM);
    int m0   = (r0 % (N_ / BM)) * BM;
    int tid  = threadIdx.x;
    int wave = tid >> 6, lane = tid & 63, quad = (lane >> 4) & 3, l16 = lane & 15;

    __shared__ __align__(16) u16 Ks[BN][D + 8];        // 17408 B
    __shared__ __align__(16) u16 Vs[D][BN + 8];        // 18432 B
    __shared__ __align__(16) u16 Psb[4][32][BN + 8];   // 18432 B
    u16* Ps = &Psb[wave][0][0];

    bf16x8 qf[2][4];
#pragma unroll
    for (int ms = 0; ms < 2; ++ms) {
        const u16* qp = Q + ((size_t)b * N_ + m0 + wave * 32 + ms * 16 + l16) * D;
#pragma unroll
        for (int kk = 0; kk < 4; ++kk)
            qf[ms][kk] = *(const bf16x8*)(qp + kk * 32 + quad * 8);
    }

    float l_r[2][4] = {{0.f, 0.f, 0.f, 0.f}, {0.f, 0.f, 0.f, 0.f}};
    f32x4 o_acc[2][8];
#pragma unroll
    for (int ms = 0; ms < 2; ++ms)
#pragma unroll
        for (int i = 0; i < 8; ++i) o_acc[ms][i] = (f32x4){0.f, 0.f, 0.f, 0.f};

    const int tiles = N_ / BN;                 // 64
    const int base = tiles / nsplit, rem = tiles % nsplit;
    const int t0 = s * base + (s < rem ? s : rem);
    const int cnt = base + (s < rem ? 1 : 0);
    const int nt0 = t0 * BN, nt1 = (t0 + cnt) * BN;

    for (int nt = nt0; nt < nt1; nt += BN) {
        const u16* kp = K + ((size_t)b * N_ + nt) * D;
#pragma unroll
        for (int it = 0; it < 4; ++it) {
            int idx = it * 256 + tid;
            int row = idx >> 4, col = (idx & 15) * 8;
            *(uint4*)&Ks[row][col] = *(const uint4*)(kp + row * D + col);
        }
#pragma unroll
        for (int it = 0; it < 4; ++it) {
            int idx = it * 256 + tid;
            int row = idx >> 3, col = (idx & 7) * 8;
            *(uint4*)&Vs[row][col] =
                *(const uint4*)(V + ((size_t)b * C2_ + row) * N_ + nt + col);
        }
        __syncthreads();

        f32x4 sc[2][4];
#pragma unroll
        for (int nn = 0; nn < 4; ++nn) {
            f32x4 a0 = (f32x4){0.f, 0.f, 0.f, 0.f};
            f32x4 a1 = (f32x4){0.f, 0.f, 0.f, 0.f};
#pragma unroll
            for (int kk = 0; kk < 4; ++kk) {
                bf16x8 kf = *(const bf16x8*)&Ks[nn * 16 + l16][kk * 32 + quad * 8];
                a0 = __builtin_amdgcn_mfma_f32_16x16x32_bf16(qf[0][kk], kf, a0, 0, 0, 0);
                a1 = __builtin_amdgcn_mfma_f32_16x16x32_bf16(qf[1][kk], kf, a1, 0, 0, 0);
            }
            sc[0][nn] = a0;
            sc[1][nn] = a1;
        }

#pragma unroll
        for (int ms = 0; ms < 2; ++ms)
#pragma unroll
            for (int nn = 0; nn < 4; ++nn)
#pragma unroll
                for (int r = 0; r < 4; ++r) {
                    float p = __builtin_amdgcn_exp2f(sc[ms][nn][r]);
                    l_r[ms][r] += p;
                    Ps[(ms * 16 + quad * 4 + r) * (BN + 8) + nn * 16 + l16] = f2bf(p);
                }

#pragma unroll
        for (int ks = 0; ks < 2; ++ks) {
            bf16x8 pf0 = *(const bf16x8*)&Ps[(l16) * (BN + 8) + ks * 32 + quad * 8];
            bf16x8 pf1 = *(const bf16x8*)&Ps[(16 + l16) * (BN + 8) + ks * 32 + quad * 8];
#pragma unroll
            for (int cs = 0; cs < 8; ++cs) {
                bf16x8 vf = *(const bf16x8*)&Vs[cs * 16 + l16][ks * 32 + quad * 8];
                o_acc[0][cs] = __builtin_amdgcn_mfma_f32_16x16x32_bf16(pf0, vf, o_acc[0][cs], 0, 0, 0);
                o_acc[1][cs] = __builtin_amdgcn_mfma_f32_16x16x32_bf16(pf1, vf, o_acc[1][cs], 0, 0, 0);
            }
        }
        __syncthreads();
    }

#pragma unroll
    for (int ms = 0; ms < 2; ++ms)
#pragma unroll
        for (int r = 0; r < 4; ++r) {
            l_r[ms][r] += __shfl_xor(l_r[ms][r], 1);
            l_r[ms][r] += __shfl_xor(l_r[ms][r], 2);
            l_r[ms][r] += __shfl_xor(l_r[ms][r], 4);
            l_r[ms][r] += __shfl_xor(l_r[ms][r], 8);
        }

    if (Opb) {
#pragma unroll
        for (int ms = 0; ms < 2; ++ms) {
#pragma unroll
            for (int cs = 0; cs < 8; ++cs)
#pragma unroll
                for (int r = 0; r < 4; ++r) {
                    size_t row = (size_t)s * (B_ * N_) + (size_t)b * N_ +
                                 m0 + wave * 32 + ms * 16 + quad * 4 + r;
                    Opb[row * C2_ + cs * 16 + l16] = f2bf(o_acc[ms][cs][r]);
                }
            if (l16 == 0)
#pragma unroll
                for (int r = 0; r < 4; ++r) {
                    size_t row = (size_t)s * (B_ * N_) + (size_t)b * N_ +
                                 m0 + wave * 32 + ms * 16 + quad * 4 + r;
                    lsum[row] = l_r[ms][r];
                }
        }
    } else {
#pragma unroll
        for (int ms = 0; ms < 2; ++ms)
#pragma unroll
            for (int cs = 0; cs < 8; ++cs)
#pragma unroll
                for (int r = 0; r < 4; ++r) {
                    float v = o_acc[ms][cs][r] / l_r[ms][r];
                    AO[((size_t)b * N_ + m0 + wave * 32 + ms * 16 + quad * 4 + r) * C2_ +
                       cs * 16 + l16] = f2bf(v);
                }
    }
}

// ---------------------------------------------------------------------------
// Kernel 2b (combine): Opb splits + lsum -> AO bf16. Pure bandwidth (~21 MB),
// grid 1024, no LDS, no barriers. Removes the combine phase from outproj.
// ---------------------------------------------------------------------------
__global__ __launch_bounds__(256) void combine_kernel(
    const u16* __restrict__ Opb, const float* __restrict__ lsum,
    u16* __restrict__ AO, int nsplit) {
    int gid = blockIdx.x * 256 + threadIdx.x;   // 262144 = 16384 rows x 16
    int row = gid >> 4, c8 = (gid & 15) * 8;
    float L = 0.f;
    for (int s = 0; s < nsplit; ++s)
        L += lsum[(size_t)s * (B_ * N_) + row];
    float inv = 1.f / L;
    float a[8] = {0.f, 0.f, 0.f, 0.f, 0.f, 0.f, 0.f, 0.f};
    for (int s = 0; s < nsplit; ++s) {
        const u16* op = Opb + ((size_t)s * (B_ * N_) + row) * C2_ + c8;
        uint4 raw = *(const uint4*)op;
        const u16* rp = (const u16*)&raw;
#pragma unroll
        for (int j = 0; j < 8; ++j) a[j] += bf2f(rp[j]);
    }
    u16 o[8];
#pragma unroll
    for (int j = 0; j < 8; ++j) o[j] = f2bf(a[j] * inv);
    *(uint4*)(AO + (size_t)row * C2_ + c8) = *(const uint4*)o;
}

// ---------------------------------------------------------------------------
// Kernel 3 (outproj): pure MFMA GEMM, NO LDS, NO barriers. af from Wob rows,
// bf direct from AO rows (both k=c2-contiguous). Grid 1024, ~4-5 blocks/CU.
// ---------------------------------------------------------------------------
__global__ __launch_bounds__(256, 2) void outproj_kernel(
    const float* __restrict__ x, const u16* __restrict__ AO,
    const u16* __restrict__ Wob, const float* __restrict__ b_out,
    float* __restrict__ y) {
    int bid = blockIdx.x;
    int b   = bid >> 8;
    int rem = bid & 255;
    int c0  = (rem >> 6) * 64;
    int n0  = (rem & 63) * 64;
    int tid = threadIdx.x;
    int wave = tid >> 6, lane = tid & 63, quad = (lane >> 4) & 3, l16 = lane & 15;

    bf16x8 af[4];
#pragma unroll
    for (int kk = 0; kk < 4; ++kk)
        af[kk] = *(const bf16x8*)(Wob + (size_t)(c0 + wave * 16 + l16) * C2_ +
                                  kk * 32 + quad * 8);

    f32x4 acc[4];
#pragma unroll
    for (int i = 0; i < 4; ++i) acc[i] = (f32x4){0.f, 0.f, 0.f, 0.f};

#pragma unroll
    for (int nn = 0; nn < 4; ++nn) {
        const u16* arow = AO + ((size_t)b * N_ + n0 + nn * 16 + l16) * C2_ + quad * 8;
        bf16x8 bfr[4];
#pragma unroll
        for (int kk = 0; kk < 4; ++kk)
            bfr[kk] = *(const bf16x8*)(arow + kk * 32);
#pragma unroll
        for (int kk = 0; kk < 4; ++kk)
            acc[nn] = __builtin_amdgcn_mfma_f32_16x16x32_bf16(af[kk], bfr[kk], acc[nn], 0, 0, 0);
    }

    int cw = c0 + wave * 16;
    float bo[4];
#pragma unroll
    for (int r = 0; r < 4; ++r) bo[r] = b_out[cw + quad * 4 + r];

#pragma unroll
    for (int nn = 0; nn < 4; ++nn)
#pragma unroll
        for (int r = 0; r < 4; ++r) {
            int c = cw + quad * 4 + r;
            size_t off = ((size_t)b * C_ + c) * N_ + n0 + nn * 16 + l16;
            y[off] = x[off] + bo[r] + acc[nn][r];
        }
}

// ---------------------------------------------------------------------------
extern "C" void kernel_launch(void* const* d_in, const int* in_sizes, int n_in,
                              void* d_out, int out_size, void* d_ws, size_t ws_size,
                              hipStream_t stream) {
    const float* x       = (const float*)d_in[0];
    const float* w_theta = (const float*)d_in[1];
    const float* b_theta = (const float*)d_in[2];
    const float* w_phi   = (const float*)d_in[3];
    const float* b_phi   = (const float*)d_in[4];
    const float* w_g     = (const float*)d_in[5];
    const float* b_g     = (const float*)d_in[6];
    const float* w_out   = (const float*)d_in[7];
    const float* b_out   = (const float*)d_in[8];
    float* y = (float*)d_out;

    const size_t SZ  = (size_t)B_ * N_ * C2_;        // 2Mi elements
    const size_t XTE = (size_t)B_ * N_ * C_;         // 4Mi elements
    u16* Q   = (u16*)d_ws;
    u16* K   = Q + SZ;
    u16* V   = K + SZ;
    u16* Wb  = V + SZ;                               // 3*128*256
    u16* Wob = Wb + 3 * 32768;                       // 256*128
    u16* XT  = Wob + 32768;                          // [B*N][C] bf16
    u16* AO  = XT + XTE;                             // combined attn out
    char* dyn = (char*)(AO + SZ);
    size_t fixedB = (4 * SZ + 4 * 32768 + XTE) * 2;  // ~24.5 MiB

    size_t perS = SZ * 2 + (size_t)B_ * N_ * 4;      // Opb bf16 + lsum per split

    int S;
    if      (ws_size >= fixedB + 4 * perS) S = 4;    // proven best split
    else if (ws_size >= fixedB + 2 * perS) S = 2;
    else                                   S = 1;

    u16*   Opb = nullptr;
    float* ls  = nullptr;
    if (S > 1) {
        Opb = (u16*)dyn;
        ls  = (float*)(Opb + (size_t)S * SZ);
    }

    prep_kernel<<<64, 256, 0, stream>>>(w_theta, w_phi, w_g, w_out, Wb, Wob);
    xpose_kernel<<<1024, 256, 0, stream>>>(x, XT);
    projx_kernel<<<1536, 256, 0, stream>>>(
        XT, Wb, b_theta, b_phi, b_g, Q, K, V);
    attn_kernel<<<B_ * (N_ / 128) * S, 256, 0, stream>>>(Q, K, V, AO, Opb, ls, S);
    if (S > 1)
        combine_kernel<<<1024, 256, 0, stream>>>(Opb, ls, AO, S);
    outproj_kernel<<<1024, 256, 0, stream>>>(x, AO, Wob, b_out, y);
}

// Round 5
// 156.250 us; speedup vs baseline: 1.1620x; 1.1620x over previous
//
#include <hip/hip_runtime.h>
#include <hip/hip_bf16.h>

#define B_  4
#define C_  256
#define C2_ 128
#define N_  4096
#define LOG2E 1.4426950408889634f

typedef unsigned short u16;
typedef __attribute__((ext_vector_type(8))) short bf16x8;  // 8 bf16 in 4 VGPRs
typedef __attribute__((ext_vector_type(4))) float f32x4;

static __device__ __forceinline__ u16 f2bf(float f) {
    return __builtin_bit_cast(u16, __float2bfloat16(f));
}
static __device__ __forceinline__ float bf2f(u16 u) {
    return __bfloat162float(__builtin_bit_cast(__hip_bfloat16, u));
}
static __device__ __forceinline__ bf16x8 cvt8(const float* p) {
    u16 t[8];
#pragma unroll
    for (int j = 0; j < 8; ++j) t[j] = f2bf(p[j]);
    return *(const bf16x8*)t;
}

// ---------------------------------------------------------------------------
// Kernel 1 (projx): fused x-transpose + 3-way MFMA projection. R-1 proven
// body (b128 LDS reads, +8/+4-col pads) with two R4 changes:
//  - h-split: grid 512, each block does one c2-half -> halves the serial
//    weight-staging phases per block, 2 blocks/CU.
//  - XCD-clustered remap: xcd = 2b + parity, so the h=0/h=1 blocks of the
//    same (b, n-tile) share an XCD (x tile + weights L2-resident).
// LDS: XTs 33792 + Ws 33792 = 67584 B -> 2 blocks/CU.
// ---------------------------------------------------------------------------
#define XW 264

__global__ __launch_bounds__(256, 2) void projx_kernel(
    const float* __restrict__ x,
    const float* __restrict__ wt, const float* __restrict__ wp,
    const float* __restrict__ wg,
    const float* __restrict__ b_theta, const float* __restrict__ b_phi,
    const float* __restrict__ b_g,
    u16* __restrict__ Q, u16* __restrict__ K, u16* __restrict__ V) {
    __shared__ __align__(16) u16 XTs[64][XW];   // 33792 B
    __shared__ __align__(16) u16 Ws[64][XW];    // 33792 B
    u16 (*Vt)[72] = (u16(*)[72])XTs;            // [64][72] overlay after af load

    // XCD-clustered remap: p%8 is the XCD (round-robin dispatch).
    int p = blockIdx.x;                 // grid 512
    int b = (p & 7) >> 1;               // batch -> XCD pair {2b, 2b+1}
    int j = ((p >> 3) << 1) | (p & 1);  // [0,128)
    int h  = j >> 6;                    // c2-half
    int n0 = (j & 63) * 64;
    int tid = threadIdx.x;
    int wave = tid >> 6, lane = tid & 63, quad = (lane >> 4) & 3, l16 = lane & 15;

    // ---- stage + transpose x tile [256 c][64 n] fp32 -> XTs[n][c] bf16 ----
#pragma unroll
    for (int it = 0; it < 8; ++it) {
        int idx = it * 256 + tid;
        int q = idx & 15, pp = idx >> 4;
        const float* r0 = x + ((size_t)b * C_ + 2 * pp) * N_ + n0 + 4 * q;
        float4 v0 = *(const float4*)r0;
        float4 v1 = *(const float4*)(r0 + N_);
        const float* f0 = (const float*)&v0;
        const float* f1 = (const float*)&v1;
#pragma unroll
        for (int jj = 0; jj < 4; ++jj) {
            unsigned pk = (unsigned)f2bf(f0[jj]) | ((unsigned)f2bf(f1[jj]) << 16);
            *(unsigned*)&XTs[4 * q + jj][2 * pp] = pk;
        }
    }
    __syncthreads();

    // A fragments: wave's 16 n-rows, resident whole kernel
    bf16x8 af[8];
#pragma unroll
    for (int ks = 0; ks < 8; ++ks)
        af[ks] = *(const bf16x8*)&XTs[wave * 16 + l16][ks * 32 + quad * 8];
    __syncthreads();   // XTs consumed -> Vt may overlay

    const float* wms[3]    = { wt, wp, wg };
    const float* biases[3] = { b_theta, b_phi, b_g };

#pragma unroll
    for (int mat = 0; mat < 3; ++mat) {
        const float* wm = wms[mat];
        const float* bias = biases[mat];
        // ---- stage this block's weight half [64 c2][256 c] fp32 -> bf16 ----
#pragma unroll
        for (int it = 0; it < 8; ++it) {
            int idx = it * 256 + tid;
            int row = idx >> 5, c8 = (idx & 31) * 8;
            const float* src = wm + (size_t)(h * 64 + row) * C_ + c8;
            float w8[8];
            *(float4*)&w8[0] = *(const float4*)src;
            *(float4*)&w8[4] = *(const float4*)(src + 4);
            *(bf16x8*)&Ws[row][c8] = cvt8(w8);
        }
        __syncthreads();

        f32x4 acc[4];
#pragma unroll
        for (int i = 0; i < 4; ++i) acc[i] = (f32x4){0.f, 0.f, 0.f, 0.f};
#pragma unroll
        for (int ct = 0; ct < 4; ++ct)
#pragma unroll
            for (int ks = 0; ks < 8; ++ks) {
                bf16x8 bf = *(const bf16x8*)&Ws[ct * 16 + l16][ks * 32 + quad * 8];
                acc[ct] = __builtin_amdgcn_mfma_f32_16x16x32_bf16(
                    af[ks], bf, acc[ct], 0, 0, 0);
            }

        if (mat < 2) {
            u16* dst = mat == 0 ? Q : K;
            float scl = mat == 0 ? LOG2E : 1.0f;
#pragma unroll
            for (int ct = 0; ct < 4; ++ct) {
                int c2 = h * 64 + ct * 16 + l16;
                float bb = bias[c2];
#pragma unroll
                for (int r = 0; r < 4; ++r) {
                    int n = n0 + wave * 16 + quad * 4 + r;
                    dst[((size_t)b * N_ + n) * C2_ + c2] =
                        f2bf((acc[ct][r] + bb) * scl);
                }
            }
        } else {
#pragma unroll
            for (int ct = 0; ct < 4; ++ct) {
                int c2l = ct * 16 + l16;
                float bb = bias[h * 64 + c2l];
#pragma unroll
                for (int r = 0; r < 4; ++r)
                    Vt[c2l][wave * 16 + quad * 4 + r] = f2bf(acc[ct][r] + bb);
            }
        }
        __syncthreads();   // Ws free for restaging / Vt complete
    }

    // cooperative V[b][h*64 + 0..63][n0..n0+63] write: 64 rows x 8 uint4
#pragma unroll
    for (int it = 0; it < 2; ++it) {
        int idx = it * 256 + tid;
        int row = idx >> 3, n8 = (idx & 7) * 8;
        *(uint4*)(V + ((size_t)b * C2_ + h * 64 + row) * N_ + n0 + n8) =
            *(const uint4*)&Vt[row][n8];
    }
}

// ---------------------------------------------------------------------------
// Kernel 2: flash attention — EXACT R-1 proven body (55 µs: b128 reads,
// +8 pads, per-wave Psb, 2 barriers/tile, S=4) with ONE change: XCD-clustered
// block remap. K+V per batch = 2 MB < 4 MiB XCD-L2, but round-robin dispatch
// gives every XCD an 8 MB (4-batch) working set -> L3 thrash on the 256 MB
// of redundant K/V staging. xcd = 2b + parity pins each batch to an XCD pair
// so staging hits L2.
// ---------------------------------------------------------------------------
__global__ __launch_bounds__(256, 2) void attn_kernel(
    const u16* __restrict__ Q, const u16* __restrict__ K,
    const u16* __restrict__ V, u16* __restrict__ AO,
    u16* __restrict__ Opb, float* __restrict__ lsum, int nsplit) {
    const int BM = 128, BN = 64, D = C2_;
    // remap: grid = 128*nsplit; per batch: 32*nsplit blocks on 2 XCDs
    int p = blockIdx.x;
    int b = (p & 7) >> 1;
    int j = ((p >> 3) << 1) | (p & 1);  // [0, 32*nsplit)
    int s  = j >> 5;
    int m0 = (j & 31) * BM;
    int tid  = threadIdx.x;
    int wave = tid >> 6, lane = tid & 63, quad = (lane >> 4) & 3, l16 = lane & 15;

    __shared__ __align__(16) u16 Ks[BN][D + 8];        // 17408 B
    __shared__ __align__(16) u16 Vs[D][BN + 8];        // 18432 B
    __shared__ __align__(16) u16 Psb[4][32][BN + 8];   // 18432 B
    u16* Ps = &Psb[wave][0][0];

    bf16x8 qf[2][4];
#pragma unroll
    for (int ms = 0; ms < 2; ++ms) {
        const u16* qp = Q + ((size_t)b * N_ + m0 + wave * 32 + ms * 16 + l16) * D;
#pragma unroll
        for (int kk = 0; kk < 4; ++kk)
            qf[ms][kk] = *(const bf16x8*)(qp + kk * 32 + quad * 8);
    }

    float l_r[2][4] = {{0.f, 0.f, 0.f, 0.f}, {0.f, 0.f, 0.f, 0.f}};
    f32x4 o_acc[2][8];
#pragma unroll
    for (int ms = 0; ms < 2; ++ms)
#pragma unroll
        for (int i = 0; i < 8; ++i) o_acc[ms][i] = (f32x4){0.f, 0.f, 0.f, 0.f};

    const int tiles = N_ / BN;                 // 64
    const int base = tiles / nsplit, rem = tiles % nsplit;
    const int t0 = s * base + (s < rem ? s : rem);
    const int cnt = base + (s < rem ? 1 : 0);
    const int nt0 = t0 * BN, nt1 = (t0 + cnt) * BN;

    for (int nt = nt0; nt < nt1; nt += BN) {
        const u16* kp = K + ((size_t)b * N_ + nt) * D;
#pragma unroll
        for (int it = 0; it < 4; ++it) {
            int idx = it * 256 + tid;
            int row = idx >> 4, col = (idx & 15) * 8;
            *(uint4*)&Ks[row][col] = *(const uint4*)(kp + row * D + col);
        }
#pragma unroll
        for (int it = 0; it < 4; ++it) {
            int idx = it * 256 + tid;
            int row = idx >> 3, col = (idx & 7) * 8;
            *(uint4*)&Vs[row][col] =
                *(const uint4*)(V + ((size_t)b * C2_ + row) * N_ + nt + col);
        }
        __syncthreads();

        f32x4 sc[2][4];
#pragma unroll
        for (int nn = 0; nn < 4; ++nn) {
            f32x4 a0 = (f32x4){0.f, 0.f, 0.f, 0.f};
            f32x4 a1 = (f32x4){0.f, 0.f, 0.f, 0.f};
#pragma unroll
            for (int kk = 0; kk < 4; ++kk) {
                bf16x8 kf = *(const bf16x8*)&Ks[nn * 16 + l16][kk * 32 + quad * 8];
                a0 = __builtin_amdgcn_mfma_f32_16x16x32_bf16(qf[0][kk], kf, a0, 0, 0, 0);
                a1 = __builtin_amdgcn_mfma_f32_16x16x32_bf16(qf[1][kk], kf, a1, 0, 0, 0);
            }
            sc[0][nn] = a0;
            sc[1][nn] = a1;
        }

#pragma unroll
        for (int ms = 0; ms < 2; ++ms)
#pragma unroll
            for (int nn = 0; nn < 4; ++nn)
#pragma unroll
                for (int r = 0; r < 4; ++r) {
                    float pv = __builtin_amdgcn_exp2f(sc[ms][nn][r]);
                    l_r[ms][r] += pv;
                    Ps[(ms * 16 + quad * 4 + r) * (BN + 8) + nn * 16 + l16] = f2bf(pv);
                }

#pragma unroll
        for (int ks = 0; ks < 2; ++ks) {
            bf16x8 pf0 = *(const bf16x8*)&Ps[(l16) * (BN + 8) + ks * 32 + quad * 8];
            bf16x8 pf1 = *(const bf16x8*)&Ps[(16 + l16) * (BN + 8) + ks * 32 + quad * 8];
#pragma unroll
            for (int cs = 0; cs < 8; ++cs) {
                bf16x8 vf = *(const bf16x8*)&Vs[cs * 16 + l16][ks * 32 + quad * 8];
                o_acc[0][cs] = __builtin_amdgcn_mfma_f32_16x16x32_bf16(pf0, vf, o_acc[0][cs], 0, 0, 0);
                o_acc[1][cs] = __builtin_amdgcn_mfma_f32_16x16x32_bf16(pf1, vf, o_acc[1][cs], 0, 0, 0);
            }
        }
        __syncthreads();
    }

#pragma unroll
    for (int ms = 0; ms < 2; ++ms)
#pragma unroll
        for (int r = 0; r < 4; ++r) {
            l_r[ms][r] += __shfl_xor(l_r[ms][r], 1);
            l_r[ms][r] += __shfl_xor(l_r[ms][r], 2);
            l_r[ms][r] += __shfl_xor(l_r[ms][r], 4);
            l_r[ms][r] += __shfl_xor(l_r[ms][r], 8);
        }

    if (Opb) {
#pragma unroll
        for (int ms = 0; ms < 2; ++ms) {
#pragma unroll
            for (int cs = 0; cs < 8; ++cs)
#pragma unroll
                for (int r = 0; r < 4; ++r) {
                    size_t row = (size_t)s * (B_ * N_) + (size_t)b * N_ +
                                 m0 + wave * 32 + ms * 16 + quad * 4 + r;
                    Opb[row * C2_ + cs * 16 + l16] = f2bf(o_acc[ms][cs][r]);
                }
            if (l16 == 0)
#pragma unroll
                for (int r = 0; r < 4; ++r) {
                    size_t row = (size_t)s * (B_ * N_) + (size_t)b * N_ +
                                 m0 + wave * 32 + ms * 16 + quad * 4 + r;
                    lsum[row] = l_r[ms][r];
                }
        }
    } else {
#pragma unroll
        for (int ms = 0; ms < 2; ++ms)
#pragma unroll
            for (int cs = 0; cs < 8; ++cs)
#pragma unroll
                for (int r = 0; r < 4; ++r) {
                    float v = o_acc[ms][cs][r] / l_r[ms][r];
                    AO[((size_t)b * N_ + m0 + wave * 32 + ms * 16 + quad * 4 + r) * C2_ +
                       cs * 16 + l16] = f2bf(v);
                }
    }
}

// ---------------------------------------------------------------------------
// Kernel 3: outproj with fused split-K combine — R-1 proven body + two R4
// changes: XCD-clustered remap (x/Opb/y per-b locality) and a y/x epilogue
// LDS bounce: acc staged as a [64 c][64 n] f32 tile (overlaying As, which is
// dead after MFMA), then 16B-vectorized x-read/add/y-write — 4x fewer
// epilogue memory instructions on the 32 MB x+y streams.
// LDS: As 17408 + Ws2 17408 + Ls 256 = 35072 -> 4 blocks/CU.
// ---------------------------------------------------------------------------
#define OW 136

__global__ __launch_bounds__(256, 4) void outproj_kernel(
    const float* __restrict__ x, const u16* __restrict__ Opb,
    const float* __restrict__ lsum, const u16* __restrict__ AO,
    const float* __restrict__ w_out, const float* __restrict__ b_out,
    float* __restrict__ y, int nsplit) {
    __shared__ __align__(16) u16 As[64][OW];     // 17408 B
    __shared__ __align__(16) u16 Ws2[64][OW];    // 17408 B
    __shared__ float Ls[64];
    float (*Yt)[68] = (float(*)[68])&As[0][0];   // overlay, 17408 B exactly

    // remap: grid 1024; per batch 256 tiles on 2 XCDs
    int p = blockIdx.x;
    int b = (p & 7) >> 1;
    int j = ((p >> 3) << 1) | (p & 1);  // [0,256)
    int c0 = (j >> 6) * 64;
    int n0 = (j & 63) * 64;
    int tid = threadIdx.x;
    int wave = tid >> 6, lane = tid & 63, quad = (lane >> 4) & 3, l16 = lane & 15;

    // ---- stage w_out tile [64 c][128 c2] fp32 -> Ws2 bf16 (coalesced) ----
#pragma unroll
    for (int it = 0; it < 4; ++it) {
        int idx = it * 256 + tid;
        int row = idx >> 4, c8 = (idx & 15) * 8;
        const float* src = w_out + (size_t)(c0 + row) * C2_ + c8;
        float w8[8];
        *(float4*)&w8[0] = *(const float4*)src;
        *(float4*)&w8[4] = *(const float4*)(src + 4);
        *(bf16x8*)&Ws2[row][c8] = cvt8(w8);
    }

    if (nsplit > 1) {   // grid-uniform branch
        if (tid < 64) {
            float L = 0.f;
            for (int s = 0; s < nsplit; ++s)
                L += lsum[(size_t)s * (B_ * N_) + (size_t)b * N_ + n0 + tid];
            Ls[tid] = 1.f / L;
        }
        __syncthreads();
#pragma unroll
        for (int it = 0; it < 4; ++it) {
            int idx = it * 256 + tid;
            int n = idx >> 4, c8 = (idx & 15) * 8;
            float a[8] = {0.f, 0.f, 0.f, 0.f, 0.f, 0.f, 0.f, 0.f};
            for (int s = 0; s < nsplit; ++s) {
                const u16* op = Opb +
                    ((size_t)s * (B_ * N_) + (size_t)b * N_ + n0 + n) * C2_ + c8;
                uint4 raw = *(const uint4*)op;
                const u16* rp = (const u16*)&raw;
#pragma unroll
                for (int jj = 0; jj < 8; ++jj) a[jj] += bf2f(rp[jj]);
            }
            float inv = Ls[n];
            u16 o[8];
#pragma unroll
            for (int jj = 0; jj < 8; ++jj) o[jj] = f2bf(a[jj] * inv);
            *(uint4*)&As[n][c8] = *(const uint4*)o;
        }
    } else {
#pragma unroll
        for (int it = 0; it < 4; ++it) {
            int idx = it * 256 + tid;
            int n = idx >> 4, c8 = (idx & 15) * 8;
            *(uint4*)&As[n][c8] =
                *(const uint4*)(AO + ((size_t)b * N_ + n0 + n) * C2_ + c8);
        }
    }
    __syncthreads();

    bf16x8 af[4];
#pragma unroll
    for (int kk = 0; kk < 4; ++kk)
        af[kk] = *(const bf16x8*)&Ws2[wave * 16 + l16][kk * 32 + quad * 8];

    f32x4 acc[4];
#pragma unroll
    for (int i = 0; i < 4; ++i) acc[i] = (f32x4){0.f, 0.f, 0.f, 0.f};

#pragma unroll
    for (int nn = 0; nn < 4; ++nn)
#pragma unroll
        for (int kk = 0; kk < 4; ++kk) {
            bf16x8 bf = *(const bf16x8*)&As[nn * 16 + l16][kk * 32 + quad * 8];
            acc[nn] = __builtin_amdgcn_mfma_f32_16x16x32_bf16(af[kk], bf, acc[nn], 0, 0, 0);
        }

    int cw = c0 + wave * 16;
    float bo[4];
#pragma unroll
    for (int r = 0; r < 4; ++r) bo[r] = b_out[cw + quad * 4 + r];

    __syncthreads();   // all waves done reading As -> Yt may overlay
#pragma unroll
    for (int nn = 0; nn < 4; ++nn)
#pragma unroll
        for (int r = 0; r < 4; ++r)
            Yt[wave * 16 + quad * 4 + r][nn * 16 + l16] = acc[nn][r] + bo[r];
    __syncthreads();

    // coalesced writeout: thread -> (c-row, 16-float seg); 16B vector ops
    {
        int row = tid >> 2, sg = (tid & 3) * 16;
        const float4* xr = (const float4*)(x + ((size_t)b * C_ + c0 + row) * N_ + n0 + sg);
        float4*       yr = (float4*)(y + ((size_t)b * C_ + c0 + row) * N_ + n0 + sg);
        const float4* tr = (const float4*)&Yt[row][sg];
#pragma unroll
        for (int jj = 0; jj < 4; ++jj) {
            float4 xv = xr[jj];
            float4 tv = tr[jj];
            yr[jj] = make_float4(xv.x + tv.x, xv.y + tv.y,
                                 xv.z + tv.z, xv.w + tv.w);
        }
    }
}

// ---------------------------------------------------------------------------
extern "C" void kernel_launch(void* const* d_in, const int* in_sizes, int n_in,
                              void* d_out, int out_size, void* d_ws, size_t ws_size,
                              hipStream_t stream) {
    const float* x       = (const float*)d_in[0];
    const float* w_theta = (const float*)d_in[1];
    const float* b_theta = (const float*)d_in[2];
    const float* w_phi   = (const float*)d_in[3];
    const float* b_phi   = (const float*)d_in[4];
    const float* w_g     = (const float*)d_in[5];
    const float* b_g     = (const float*)d_in[6];
    const float* w_out   = (const float*)d_in[7];
    const float* b_out   = (const float*)d_in[8];
    float* y = (float*)d_out;

    const size_t SZ = (size_t)B_ * N_ * C2_;        // 2Mi elements
    u16* Q = (u16*)d_ws;
    u16* K = Q + SZ;
    u16* V = K + SZ;
    char* dyn = (char*)(V + SZ);
    size_t fixedB = 3 * SZ * 2;                      // 12 MiB

    size_t perS = SZ * 2 + (size_t)B_ * N_ * 4;      // Opb bf16 + lsum per split

    int S;
    if      (ws_size >= fixedB + 4 * perS) S = 4;    // proven best split
    else if (ws_size >= fixedB + 2 * perS) S = 2;
    else                                   S = 1;

    u16*   AO  = (u16*)dyn;       // used only when S == 1
    u16*   Opb = nullptr;
    float* ls  = nullptr;
    if (S > 1) {
        Opb = (u16*)dyn;          // aliases AO (AO unused when split)
        ls  = (float*)(Opb + (size_t)S * SZ);
    }

    projx_kernel<<<B_ * (N_ / 64) * 2, 256, 0, stream>>>(
        x, w_theta, w_phi, w_g, b_theta, b_phi, b_g, Q, K, V);
    attn_kernel<<<B_ * (N_ / 128) * S, 256, 0, stream>>>(Q, K, V, AO, Opb, ls, S);
    outproj_kernel<<<B_ * (C_ / 64) * (N_ / 64), 256, 0, stream>>>(
        x, Opb, ls, AO, w_out, b_out, y, S);
}